// Round 7
// baseline (263.015 us; speedup 1.0000x reference)
//
#include <hip/hip_runtime.h>
#include <hip/hip_fp16.h>
#include <math.h>

#define N_NODES 100000
#define N_EDGES 1600000
#define IN_F    128
#define OUT_F   64
#define NB        ((N_NODES + 255) / 256)        // 391 linear blocks
#define K_BKT     196                            // dst buckets of 512 nodes
#define BKT_SHIFT 9
#define BKT_NODES 512
#define CHUNK_CNT 8192
#define CNT_BLKS  ((N_EDGES + CHUNK_CNT - 1) / CHUNK_CNT)  // 196
#define CHUNK     4096                           // partition block edge count
#define PBLKS     ((N_EDGES + CHUNK - 1) / CHUNK)          // 391

// ---------------- workspace layout (4-byte units) ----------------
// fth      : N_NODES*OUT_F/2  (fp16 projected features, 12.8 MB)
// staging  : N_EDGES uint     (packed src|dloc<<17, bucket-sorted, 6.4 MB)
// edge_src : N_EDGES          (final CSR src ids)
// btot     : K_BKT ; bucket_start : K_BKT+1 ; bcursor : K_BKT
// row_start: N_NODES+1

// blocks [0,NB): linear (wave-outer-product, feat staged in LDS coalesced).
// blocks [NB,NB+CNT_BLKS): bucket histogram of dst -> btot (global).
__global__ __launch_bounds__(256) void linear_count_kernel(const float* __restrict__ feat,
                                                           const float* __restrict__ W,
                                                           __half* __restrict__ fth,
                                                           const int* __restrict__ dst,
                                                           int* __restrict__ btot) {
    __shared__ alignas(16) unsigned char smem[49152];   // 48 KB
    int t = threadIdx.x;
    if (blockIdx.x >= NB) {
        int* hist = (int*)smem;                 // 196 ints
        for (int j = t; j < K_BKT; j += 256) hist[j] = 0;
        __syncthreads();
        int b0 = (blockIdx.x - NB) * CHUNK_CNT;
        int e0 = min(b0 + CHUNK_CNT, N_EDGES);
        for (int i = b0 + t; i < e0; i += 256)
            atomicAdd(&hist[dst[i] >> BKT_SHIFT], 1);
        __syncthreads();
        for (int j = t; j < K_BKT; j += 256) {
            int h = hist[j];
            if (h) atomicAdd(&btot[j], h);
        }
        return;
    }
    // ---- linear: ft = feat @ W (fp16 out) ----
    float* Wf    = (float*)smem;                // 8192 floats = 32 KB, W[k][c]
    float* ftile = Wf + IN_F * OUT_F;           // 32 rows x 128 = 16 KB
    const float4* W4 = (const float4*)W;
    float4* Wl4 = (float4*)Wf;
    for (int i = t; i < IN_F * OUT_F / 4; i += 256) Wl4[i] = W4[i];

    int wv = t >> 6, c = t & 63;
    int Rbase = blockIdx.x * 256;
    for (int tile = 0; tile < 8; ++tile) {
        __syncthreads();                        // W ready / previous ftile consumed
        int r0 = Rbase + tile * 32;
        const float4* fsrc = (const float4*)(feat + (size_t)r0 * IN_F);
        int lim = (N_NODES - r0) * (IN_F / 4);  // float4s available (may be <=0)
        float4* ft4 = (float4*)ftile;
        for (int i = t; i < 32 * IN_F / 4; i += 256)
            ft4[i] = (i < lim) ? fsrc[i] : make_float4(0.f, 0.f, 0.f, 0.f);
        __syncthreads();

        float a[8];
#pragma unroll
        for (int j = 0; j < 8; ++j) a[j] = 0.f;
        for (int k4 = 0; k4 < IN_F / 4; ++k4) {
            float w0 = Wf[(4 * k4 + 0) * OUT_F + c];
            float w1 = Wf[(4 * k4 + 1) * OUT_F + c];
            float w2 = Wf[(4 * k4 + 2) * OUT_F + c];
            float w3 = Wf[(4 * k4 + 3) * OUT_F + c];
#pragma unroll
            for (int j = 0; j < 8; ++j) {
                float4 f = ((const float4*)(ftile + (wv * 8 + j) * IN_F))[k4];
                a[j] += f.x * w0 + f.y * w1 + f.z * w2 + f.w * w3;
            }
        }
        int r = r0 + wv * 8;
#pragma unroll
        for (int j = 0; j < 8; ++j) {
            int row = r + j;
            if (row < N_NODES)
                fth[(size_t)row * OUT_F + c] = __float2half_rn(a[j]);
        }
    }
}

// 1 block: exclusive scan of bucket totals -> bucket_start + bcursor init.
__global__ __launch_bounds__(256) void scan_kernel(const int* __restrict__ btot,
                                                   int* __restrict__ bucket_start,
                                                   int* __restrict__ bcursor,
                                                   int* __restrict__ row_start) {
    __shared__ int sc[256];
    int t = threadIdx.x;
    int v = (t < K_BKT) ? btot[t] : 0;
    sc[t] = v;
    __syncthreads();
    for (int off = 1; off < 256; off <<= 1) {
        int add = (t >= off) ? sc[t - off] : 0;
        __syncthreads();
        sc[t] += add;
        __syncthreads();
    }
    if (t < K_BKT) {
        int excl = sc[t] - v;
        bucket_start[t] = excl;
        bcursor[t] = excl;
    }
    if (t == 0) { bucket_start[K_BKT] = N_EDGES; row_start[N_NODES] = N_EDGES; }
}

// in-LDS counting sort per 4096-edge block -> bucket-contiguous runs (~21
// entries) written coalesced to staging. One reservation atomic per
// (block,bucket) spread over 196 counters — no hot line.
__global__ __launch_bounds__(256) void partition_kernel(const int* __restrict__ src,
                                                        const int* __restrict__ dst,
                                                        int* __restrict__ bcursor,
                                                        unsigned* __restrict__ staging) {
    __shared__ int hist[256], lbase[256], gbase[256], sc[256];
    __shared__ unsigned sval[CHUNK];
    __shared__ int spos[CHUNK];
    int t = threadIdx.x;
    hist[t] = 0;
    __syncthreads();
    int beg = blockIdx.x * CHUNK;
    int end = min(beg + CHUNK, N_EDGES);
    for (int i = beg + t; i < end; i += 256)
        atomicAdd(&hist[dst[i] >> BKT_SHIFT], 1);
    __syncthreads();
    int v = hist[t];
    sc[t] = v;
    __syncthreads();
    for (int off = 1; off < 256; off <<= 1) {
        int add = (t >= off) ? sc[t - off] : 0;
        __syncthreads();
        sc[t] += add;
        __syncthreads();
    }
    lbase[t] = sc[t] - v;                        // block-local exclusive
    if (t < K_BKT && v) gbase[t] = atomicAdd(&bcursor[t], v);
    hist[t] = 0;                                 // reuse as rank counter
    __syncthreads();
    for (int i = beg + t; i < end; i += 256) {
        int s = src[i], d = dst[i];
        int b = d >> BKT_SHIFT;
        int r = atomicAdd(&hist[b], 1);
        int lp = lbase[b] + r;
        sval[lp] = (unsigned)s | ((unsigned)(d & (BKT_NODES - 1)) << 17);
        spos[lp] = gbase[b] + r;
    }
    __syncthreads();
    int n = end - beg;
    for (int p = t; p < n; p += 256) staging[spos[p]] = sval[p];
}

// one block per bucket: per-node counts + scan -> row_start, then place src
// ids into exact CSR slots. One block -> one XCD -> full dirty lines.
__global__ __launch_bounds__(256) void place_kernel(const unsigned* __restrict__ staging,
                                                    const int* __restrict__ bucket_start,
                                                    int* __restrict__ row_start,
                                                    int* __restrict__ edge_src) {
    __shared__ int cnt[BKT_NODES], sc[256], lcur[BKT_NODES];
    int t = threadIdx.x;
    cnt[t] = 0; cnt[t + 256] = 0;
    __syncthreads();
    int base = bucket_start[blockIdx.x];
    int end  = bucket_start[blockIdx.x + 1];
    for (int i = base + t; i < end; i += 256)
        atomicAdd(&cnt[staging[i] >> 17], 1);
    __syncthreads();
    int v0 = cnt[2 * t], v1 = cnt[2 * t + 1];
    int ts = v0 + v1;
    sc[t] = ts;
    __syncthreads();
    for (int off = 1; off < 256; off <<= 1) {
        int add = (t >= off) ? sc[t - off] : 0;
        __syncthreads();
        sc[t] += add;
        __syncthreads();
    }
    int excl = sc[t] - ts;
    int node0 = blockIdx.x * BKT_NODES;
    lcur[2 * t]     = base + excl;
    lcur[2 * t + 1] = base + excl + v0;
    if (node0 + 2 * t     < N_NODES) row_start[node0 + 2 * t]     = base + excl;
    if (node0 + 2 * t + 1 < N_NODES) row_start[node0 + 2 * t + 1] = base + excl + v0;
    __syncthreads();
    for (int i = base + t; i < end; i += 256) {
        unsigned u = staging[i];
        int pos = atomicAdd(&lcur[u >> 17], 1);
        edge_src[pos] = (int)(u & 0x1FFFFu);
    }
}

// one wave per dst node. 16 lanes/edge (4 channels/lane, 8B loads), 8 edges
// in flight per wave, reduce depth 4; quarter-states merged once at the end.
__global__ __launch_bounds__(256) void fused_node_kernel(const __half* __restrict__ fth,
                                                         const int* __restrict__ row_start,
                                                         const int* __restrict__ edge_src,
                                                         float* __restrict__ out) {
    int wave = (blockIdx.x * 256 + threadIdx.x) >> 6;
    int lane = threadIdx.x & 63;
    if (wave >= N_NODES) return;
    int q = lane >> 4, ql = lane & 15;

    int beg = row_start[wave];
    int end = row_start[wave + 1];

    float2 rd = *(const float2*)(fth + (size_t)wave * OUT_F + 4 * ql);
    __half2 d01 = *(__half2*)&rd.x, d23 = *(__half2*)&rd.y;
    float fd0 = __half2float(d01.x), fd1 = __half2float(d01.y);
    float fd2 = __half2float(d23.x), fd3 = __half2float(d23.y);

    float m = -1e30f, l = 0.f;
    float a0 = 0.f, a1 = 0.f, a2 = 0.f, a3 = 0.f;

    for (int i = beg; i < end; i += 8) {
        int eA = i + q, eB = i + 4 + q;
        bool vA = eA < end, vB = eB < end;
        int sA = edge_src[vA ? eA : (end - 1)];
        int sB = edge_src[vB ? eB : (end - 1)];
        float2 rA = *(const float2*)(fth + (size_t)sA * OUT_F + 4 * ql);
        float2 rB = *(const float2*)(fth + (size_t)sB * OUT_F + 4 * ql);
        __half2 A01 = *(__half2*)&rA.x, A23 = *(__half2*)&rA.y;
        __half2 B01 = *(__half2*)&rB.x, B23 = *(__half2*)&rB.y;
        float vA0 = __half2float(A01.x), vA1 = __half2float(A01.y);
        float vA2 = __half2float(A23.x), vA3 = __half2float(A23.y);
        float vB0 = __half2float(B01.x), vB1 = __half2float(B01.y);
        float vB2 = __half2float(B23.x), vB3 = __half2float(B23.y);

        float pA = vA0 * fd0 + vA1 * fd1 + vA2 * fd2 + vA3 * fd3;
        float pB = vB0 * fd0 + vB1 * fd1 + vB2 * fd2 + vB3 * fd3;
#pragma unroll
        for (int d = 1; d < 16; d <<= 1) {
            pA += __shfl_xor(pA, d);
            pB += __shfl_xor(pB, d);
        }
        if (!vA) pA = -1e30f;
        if (!vB) pB = -1e30f;
        float nm = fmaxf(fmaxf(m, pA), pB);
        float alpha = __expf(m - nm);
        float wA = vA ? __expf(pA - nm) : 0.f;
        float wB = vB ? __expf(pB - nm) : 0.f;
        l = l * alpha + (wA + wB);
        a0 = a0 * alpha + wA * vA0 + wB * vB0;
        a1 = a1 * alpha + wA * vA1 + wB * vB1;
        a2 = a2 * alpha + wA * vA2 + wB * vB2;
        a3 = a3 * alpha + wA * vA3 + wB * vB3;
        m = nm;
    }

#pragma unroll
    for (int d = 16; d <= 32; d <<= 1) {
        float m2 = __shfl_xor(m, d), l2 = __shfl_xor(l, d);
        float b0 = __shfl_xor(a0, d), b1 = __shfl_xor(a1, d);
        float b2 = __shfl_xor(a2, d), b3 = __shfl_xor(a3, d);
        float M = fmaxf(m, m2);
        float e1 = __expf(m - M), e2 = __expf(m2 - M);
        l = l * e1 + l2 * e2;
        a0 = a0 * e1 + b0 * e2;
        a1 = a1 * e1 + b1 * e2;
        a2 = a2 * e1 + b2 * e2;
        a3 = a3 * e1 + b3 * e2;
        m = M;
    }
    if (q == 0) {
        float inv = (l > 0.f) ? 1.f / l : 0.f;
        *(float4*)(out + (size_t)wave * OUT_F + 4 * ql) =
            make_float4(a0 * inv, a1 * inv, a2 * inv, a3 * inv);
    }
}

extern "C" void kernel_launch(void* const* d_in, const int* in_sizes, int n_in,
                              void* d_out, int out_size, void* d_ws, size_t ws_size,
                              hipStream_t stream) {
    const float* feat = (const float*)d_in[0];
    const float* W    = (const float*)d_in[1];
    const int*   src  = (const int*)d_in[2];
    const int*   dst  = (const int*)d_in[3];
    float* out = (float*)d_out;

    __half*   fth          = (__half*)d_ws;
    unsigned* staging      = (unsigned*)((int*)d_ws + (size_t)N_NODES * OUT_F / 2);
    int*      edge_src     = (int*)(staging + N_EDGES);
    int*      btot         = edge_src + N_EDGES;
    int*      bucket_start = btot + K_BKT;
    int*      bcursor      = bucket_start + K_BKT + 1;
    int*      row_start    = bcursor + K_BKT;

    hipMemsetAsync(btot, 0, K_BKT * sizeof(int), stream);
    linear_count_kernel<<<NB + CNT_BLKS, 256, 0, stream>>>(feat, W, fth, dst, btot);
    scan_kernel<<<1, 256, 0, stream>>>(btot, bucket_start, bcursor, row_start);
    partition_kernel<<<PBLKS, 256, 0, stream>>>(src, dst, bcursor, staging);
    place_kernel<<<K_BKT, 256, 0, stream>>>(staging, bucket_start, row_start, edge_src);
    fused_node_kernel<<<(N_NODES * 64) / 256, 256, 0, stream>>>(fth, row_start, edge_src, out);
}

// Round 8
// 219.868 us; speedup vs baseline: 1.1962x; 1.1962x over previous
//
#include <hip/hip_runtime.h>
#include <hip/hip_fp16.h>
#include <math.h>

#define N_NODES 100000
#define N_EDGES 1600000
#define IN_F    128
#define OUT_F   64
#define K_BKT     196                            // dst buckets of 512 nodes
#define BKT_SHIFT 9
#define BKT_NODES 512
#define CHUNK_CNT 8192
#define CNT_BLKS  ((N_EDGES + CHUNK_CNT - 1) / CHUNK_CNT)  // 196
#define CHUNK     4096                           // partition block edge count
#define PBLKS     ((N_EDGES + CHUNK - 1) / CHUNK)          // 391
#define LTILES    (N_NODES / 16)                 // 6250 exact 16-row MFMA tiles
#define LBLKS     ((LTILES + 3) / 4)             // 1563 (4 waves/block)

typedef _Float16 half8 __attribute__((ext_vector_type(8)));
typedef float    f32x4 __attribute__((ext_vector_type(4)));

// ---------------- workspace layout (4-byte units) ----------------
// fth      : N_NODES*OUT_F/2  (fp16 projected features, 12.8 MB)
// staging  : N_EDGES uint     (packed src|dloc<<17, bucket-sorted, 6.4 MB)
// edge_src : N_EDGES          (final CSR src ids)
// btot     : K_BKT ; bucket_start : K_BKT+1 ; bcursor : K_BKT
// row_start: N_NODES+1

// per-chunk LDS histogram of dst buckets -> btot
__global__ __launch_bounds__(256) void count_kernel(const int* __restrict__ dst,
                                                    int* __restrict__ btot) {
    __shared__ int hist[K_BKT];
    int t = threadIdx.x;
    for (int j = t; j < K_BKT; j += 256) hist[j] = 0;
    __syncthreads();
    int b0 = blockIdx.x * CHUNK_CNT;
    int e0 = min(b0 + CHUNK_CNT, N_EDGES);
    for (int i = b0 + t; i < e0; i += 256)
        atomicAdd(&hist[dst[i] >> BKT_SHIFT], 1);
    __syncthreads();
    for (int j = t; j < K_BKT; j += 256) {
        int h = hist[j];
        if (h) atomicAdd(&btot[j], h);
    }
}

// 1 block: exclusive scan of bucket totals -> bucket_start + bcursor init.
__global__ __launch_bounds__(256) void scan_kernel(const int* __restrict__ btot,
                                                   int* __restrict__ bucket_start,
                                                   int* __restrict__ bcursor,
                                                   int* __restrict__ row_start) {
    __shared__ int sc[256];
    int t = threadIdx.x;
    int v = (t < K_BKT) ? btot[t] : 0;
    sc[t] = v;
    __syncthreads();
    for (int off = 1; off < 256; off <<= 1) {
        int add = (t >= off) ? sc[t - off] : 0;
        __syncthreads();
        sc[t] += add;
        __syncthreads();
    }
    if (t < K_BKT) {
        int excl = sc[t] - v;
        bucket_start[t] = excl;
        bcursor[t] = excl;
    }
    if (t == 0) { bucket_start[K_BKT] = N_EDGES; row_start[N_NODES] = N_EDGES; }
}

// blocks [0,PBLKS): in-LDS counting sort of a 4096-edge chunk into bucket-
// contiguous staging runs (coalesced writes, no hot atomics).
// blocks [PBLKS,..): MFMA fp16 linear — wave = 16-row tile of ft = feat @ W.
__global__ __launch_bounds__(256) void partition_linear_kernel(const int* __restrict__ src,
                                                               const int* __restrict__ dst,
                                                               int* __restrict__ bcursor,
                                                               unsigned* __restrict__ staging,
                                                               const float* __restrict__ feat,
                                                               const float* __restrict__ W,
                                                               __half* __restrict__ fth) {
    __shared__ int hist[256], lbase[256], gbase[256], sc[256];
    __shared__ unsigned sval[CHUNK];
    __shared__ int spos[CHUNK];
    int t = threadIdx.x;
    if (blockIdx.x < PBLKS) {
        hist[t] = 0;
        __syncthreads();
        int beg = blockIdx.x * CHUNK;
        int end = min(beg + CHUNK, N_EDGES);
        for (int i = beg + t; i < end; i += 256)
            atomicAdd(&hist[dst[i] >> BKT_SHIFT], 1);
        __syncthreads();
        int v = hist[t];
        sc[t] = v;
        __syncthreads();
        for (int off = 1; off < 256; off <<= 1) {
            int add = (t >= off) ? sc[t - off] : 0;
            __syncthreads();
            sc[t] += add;
            __syncthreads();
        }
        lbase[t] = sc[t] - v;                    // block-local exclusive
        if (t < K_BKT && v) gbase[t] = atomicAdd(&bcursor[t], v);
        hist[t] = 0;                             // reuse as rank counter
        __syncthreads();
        for (int i = beg + t; i < end; i += 256) {
            int s = src[i], d = dst[i];
            int b = d >> BKT_SHIFT;
            int r = atomicAdd(&hist[b], 1);
            int lp = lbase[b] + r;
            sval[lp] = (unsigned)s | ((unsigned)(d & (BKT_NODES - 1)) << 17);
            spos[lp] = gbase[b] + r;
        }
        __syncthreads();
        int n = end - beg;
        for (int p = t; p < n; p += 256) staging[spos[p]] = sval[p];
        return;
    }
    // ---- MFMA linear: one wave per 16-row tile ----
    int gwave = (blockIdx.x - PBLKS) * 4 + (t >> 6);
    if (gwave >= LTILES) return;
    int lane = t & 63;
    int m = lane & 15, kg = lane >> 4;
    int r0 = gwave * 16;

    // B fragments: B[k][n], n = lane&15, k = kb*32 + kg*8 + j  (W is 32 KB,
    // identical for every wave -> L1/L2-resident after first touch)
    half8 fb[4][4];
#pragma unroll
    for (int kb = 0; kb < 4; ++kb)
#pragma unroll
        for (int nb = 0; nb < 4; ++nb) {
            const float* wp = W + (size_t)(kb * 32 + kg * 8) * OUT_F + nb * 16 + m;
#pragma unroll
            for (int j = 0; j < 8; ++j)
                fb[kb][nb][j] = (_Float16)wp[j * OUT_F];
        }

    f32x4 acc[4];
#pragma unroll
    for (int nb = 0; nb < 4; ++nb) acc[nb] = (f32x4){0.f, 0.f, 0.f, 0.f};

#pragma unroll
    for (int kb = 0; kb < 4; ++kb) {
        // A fragment: A[m][k], row = r0+m, k = kb*32 + kg*8 + j (8 consec floats)
        const float4* ap = (const float4*)(feat + (size_t)(r0 + m) * IN_F + kb * 32 + kg * 8);
        float4 a0 = ap[0], a1 = ap[1];
        half8 fa = {(_Float16)a0.x, (_Float16)a0.y, (_Float16)a0.z, (_Float16)a0.w,
                    (_Float16)a1.x, (_Float16)a1.y, (_Float16)a1.z, (_Float16)a1.w};
#pragma unroll
        for (int nb = 0; nb < 4; ++nb)
            acc[nb] = __builtin_amdgcn_mfma_f32_16x16x32_f16(fa, fb[kb][nb], acc[nb], 0, 0, 0);
    }
    // D: col = lane&15, row = (lane>>4)*4 + i
#pragma unroll
    for (int nb = 0; nb < 4; ++nb)
#pragma unroll
        for (int i = 0; i < 4; ++i)
            fth[(size_t)(r0 + kg * 4 + i) * OUT_F + nb * 16 + m] = __float2half_rn(acc[nb][i]);
}

// one block per bucket: per-node counts + scan -> row_start, then place src
// ids into exact CSR slots. One block -> one XCD -> full dirty lines.
__global__ __launch_bounds__(256) void place_kernel(const unsigned* __restrict__ staging,
                                                    const int* __restrict__ bucket_start,
                                                    int* __restrict__ row_start,
                                                    int* __restrict__ edge_src) {
    __shared__ int cnt[BKT_NODES], sc[256], lcur[BKT_NODES];
    int t = threadIdx.x;
    cnt[t] = 0; cnt[t + 256] = 0;
    __syncthreads();
    int base = bucket_start[blockIdx.x];
    int end  = bucket_start[blockIdx.x + 1];
    for (int i = base + t; i < end; i += 256)
        atomicAdd(&cnt[staging[i] >> 17], 1);
    __syncthreads();
    int v0 = cnt[2 * t], v1 = cnt[2 * t + 1];
    int ts = v0 + v1;
    sc[t] = ts;
    __syncthreads();
    for (int off = 1; off < 256; off <<= 1) {
        int add = (t >= off) ? sc[t - off] : 0;
        __syncthreads();
        sc[t] += add;
        __syncthreads();
    }
    int excl = sc[t] - ts;
    int node0 = blockIdx.x * BKT_NODES;
    lcur[2 * t]     = base + excl;
    lcur[2 * t + 1] = base + excl + v0;
    if (node0 + 2 * t     < N_NODES) row_start[node0 + 2 * t]     = base + excl;
    if (node0 + 2 * t + 1 < N_NODES) row_start[node0 + 2 * t + 1] = base + excl + v0;
    __syncthreads();
    for (int i = base + t; i < end; i += 256) {
        unsigned u = staging[i];
        int pos = atomicAdd(&lcur[u >> 17], 1);
        edge_src[pos] = (int)(u & 0x1FFFFu);
    }
}

// one wave per dst node. 16 lanes/edge (4 channels/lane, 8B loads), 8 edges
// in flight per wave, reduce depth 4; quarter-states merged once at the end.
__global__ __launch_bounds__(256) void fused_node_kernel(const __half* __restrict__ fth,
                                                         const int* __restrict__ row_start,
                                                         const int* __restrict__ edge_src,
                                                         float* __restrict__ out) {
    int wave = (blockIdx.x * 256 + threadIdx.x) >> 6;
    int lane = threadIdx.x & 63;
    if (wave >= N_NODES) return;
    int q = lane >> 4, ql = lane & 15;

    int beg = row_start[wave];
    int end = row_start[wave + 1];

    float2 rd = *(const float2*)(fth + (size_t)wave * OUT_F + 4 * ql);
    __half2 d01 = *(__half2*)&rd.x, d23 = *(__half2*)&rd.y;
    float fd0 = __half2float(d01.x), fd1 = __half2float(d01.y);
    float fd2 = __half2float(d23.x), fd3 = __half2float(d23.y);

    float m = -1e30f, l = 0.f;
    float a0 = 0.f, a1 = 0.f, a2 = 0.f, a3 = 0.f;

    for (int i = beg; i < end; i += 8) {
        int eA = i + q, eB = i + 4 + q;
        bool vA = eA < end, vB = eB < end;
        int sA = edge_src[vA ? eA : (end - 1)];
        int sB = edge_src[vB ? eB : (end - 1)];
        float2 rA = *(const float2*)(fth + (size_t)sA * OUT_F + 4 * ql);
        float2 rB = *(const float2*)(fth + (size_t)sB * OUT_F + 4 * ql);
        __half2 A01 = *(__half2*)&rA.x, A23 = *(__half2*)&rA.y;
        __half2 B01 = *(__half2*)&rB.x, B23 = *(__half2*)&rB.y;
        float vA0 = __half2float(A01.x), vA1 = __half2float(A01.y);
        float vA2 = __half2float(A23.x), vA3 = __half2float(A23.y);
        float vB0 = __half2float(B01.x), vB1 = __half2float(B01.y);
        float vB2 = __half2float(B23.x), vB3 = __half2float(B23.y);

        float pA = vA0 * fd0 + vA1 * fd1 + vA2 * fd2 + vA3 * fd3;
        float pB = vB0 * fd0 + vB1 * fd1 + vB2 * fd2 + vB3 * fd3;
#pragma unroll
        for (int d = 1; d < 16; d <<= 1) {
            pA += __shfl_xor(pA, d);
            pB += __shfl_xor(pB, d);
        }
        if (!vA) pA = -1e30f;
        if (!vB) pB = -1e30f;
        float nm = fmaxf(fmaxf(m, pA), pB);
        float alpha = __expf(m - nm);
        float wA = vA ? __expf(pA - nm) : 0.f;
        float wB = vB ? __expf(pB - nm) : 0.f;
        l = l * alpha + (wA + wB);
        a0 = a0 * alpha + wA * vA0 + wB * vB0;
        a1 = a1 * alpha + wA * vA1 + wB * vB1;
        a2 = a2 * alpha + wA * vA2 + wB * vB2;
        a3 = a3 * alpha + wA * vA3 + wB * vB3;
        m = nm;
    }

#pragma unroll
    for (int d = 16; d <= 32; d <<= 1) {
        float m2 = __shfl_xor(m, d), l2 = __shfl_xor(l, d);
        float b0 = __shfl_xor(a0, d), b1 = __shfl_xor(a1, d);
        float b2 = __shfl_xor(a2, d), b3 = __shfl_xor(a3, d);
        float M = fmaxf(m, m2);
        float e1 = __expf(m - M), e2 = __expf(m2 - M);
        l = l * e1 + l2 * e2;
        a0 = a0 * e1 + b0 * e2;
        a1 = a1 * e1 + b1 * e2;
        a2 = a2 * e1 + b2 * e2;
        a3 = a3 * e1 + b3 * e2;
        m = M;
    }
    if (q == 0) {
        float inv = (l > 0.f) ? 1.f / l : 0.f;
        *(float4*)(out + (size_t)wave * OUT_F + 4 * ql) =
            make_float4(a0 * inv, a1 * inv, a2 * inv, a3 * inv);
    }
}

extern "C" void kernel_launch(void* const* d_in, const int* in_sizes, int n_in,
                              void* d_out, int out_size, void* d_ws, size_t ws_size,
                              hipStream_t stream) {
    const float* feat = (const float*)d_in[0];
    const float* W    = (const float*)d_in[1];
    const int*   src  = (const int*)d_in[2];
    const int*   dst  = (const int*)d_in[3];
    float* out = (float*)d_out;

    __half*   fth          = (__half*)d_ws;
    unsigned* staging      = (unsigned*)((int*)d_ws + (size_t)N_NODES * OUT_F / 2);
    int*      edge_src     = (int*)(staging + N_EDGES);
    int*      btot         = edge_src + N_EDGES;
    int*      bucket_start = btot + K_BKT;
    int*      bcursor      = bucket_start + K_BKT + 1;
    int*      row_start    = bcursor + K_BKT;

    hipMemsetAsync(btot, 0, K_BKT * sizeof(int), stream);
    count_kernel<<<CNT_BLKS, 256, 0, stream>>>(dst, btot);
    scan_kernel<<<1, 256, 0, stream>>>(btot, bucket_start, bcursor, row_start);
    partition_linear_kernel<<<PBLKS + LBLKS, 256, 0, stream>>>(src, dst, bcursor, staging,
                                                               feat, W, fth);
    place_kernel<<<K_BKT, 256, 0, stream>>>(staging, bucket_start, row_start, edge_src);
    fused_node_kernel<<<(N_NODES * 64) / 256, 256, 0, stream>>>(fth, row_start, edge_src, out);
}

// Round 9
// 201.559 us; speedup vs baseline: 1.3049x; 1.0908x over previous
//
#include <hip/hip_runtime.h>
#include <hip/hip_fp16.h>
#include <math.h>

#define N_NODES 100000
#define N_EDGES 1600000
#define IN_F    128
#define OUT_F   64
#define K_BKT     196                            // dst buckets of 512 nodes
#define BKT_SHIFT 9
#define BKT_NODES 512
#define BKT_CAP   10240                          // slots per bucket (E=8192, +22 sigma)
#define CHUNK     4096                           // partition block edge count
#define PBLKS     ((N_EDGES + CHUNK - 1) / CHUNK)          // 391
#define LTILES    (N_NODES / 16)                 // 6250 exact 16-row MFMA tiles
#define LBLKS     ((LTILES + 3) / 4)             // 1563 (4 waves/block)

typedef _Float16 half8 __attribute__((ext_vector_type(8)));
typedef _Float16 h2v   __attribute__((ext_vector_type(2)));
typedef float    f32x4 __attribute__((ext_vector_type(4)));
typedef float    f2v   __attribute__((ext_vector_type(2)));

// ---------------- workspace layout (4-byte units) ----------------
// fth      : N_NODES*OUT_F/2       (fp16 projected features, 12.8 MB)
// staging  : K_BKT*BKT_CAP uint    (packed src|dloc<<17, capacity layout, 8 MB)
// edge_src : K_BKT*BKT_CAP int     (CSR src ids, capacity layout, 8 MB)
// bcursor  : K_BKT                 (zero-init; after partition = bucket count)
// row_beg/row_end : N_NODES each

// blocks [0,PBLKS): in-LDS counting sort of a 4096-edge chunk into bucket
// regions at b*BKT_CAP (reservation atomics on 196 spread counters).
// blocks [PBLKS,..): MFMA fp16 linear — wave = 16-row tile of ft = feat @ W.
__global__ __launch_bounds__(256) void partition_linear_kernel(const int* __restrict__ src,
                                                               const int* __restrict__ dst,
                                                               int* __restrict__ bcursor,
                                                               unsigned* __restrict__ staging,
                                                               const float* __restrict__ feat,
                                                               const float* __restrict__ W,
                                                               __half* __restrict__ fth) {
    __shared__ int hist[256], lbase[256], gbase[256], sc[256];
    __shared__ unsigned sval[CHUNK];
    __shared__ int spos[CHUNK];
    int t = threadIdx.x;
    if (blockIdx.x < PBLKS) {
        hist[t] = 0;
        __syncthreads();
        int beg = blockIdx.x * CHUNK;
        int end = min(beg + CHUNK, N_EDGES);
        for (int i = beg + t; i < end; i += 256)
            atomicAdd(&hist[dst[i] >> BKT_SHIFT], 1);
        __syncthreads();
        int v = hist[t];
        sc[t] = v;
        __syncthreads();
        for (int off = 1; off < 256; off <<= 1) {
            int add = (t >= off) ? sc[t - off] : 0;
            __syncthreads();
            sc[t] += add;
            __syncthreads();
        }
        lbase[t] = sc[t] - v;                    // block-local exclusive
        if (t < K_BKT && v) gbase[t] = t * BKT_CAP + atomicAdd(&bcursor[t], v);
        hist[t] = 0;                             // reuse as rank counter
        __syncthreads();
        for (int i = beg + t; i < end; i += 256) {
            int s = src[i], d = dst[i];
            int b = d >> BKT_SHIFT;
            int r = atomicAdd(&hist[b], 1);
            int lp = lbase[b] + r;
            sval[lp] = (unsigned)s | ((unsigned)(d & (BKT_NODES - 1)) << 17);
            spos[lp] = gbase[b] + r;
        }
        __syncthreads();
        int n = end - beg;
        for (int p = t; p < n; p += 256) staging[spos[p]] = sval[p];
        return;
    }
    // ---- MFMA linear: one wave per 16-row tile ----
    int gwave = (blockIdx.x - PBLKS) * 4 + (t >> 6);
    if (gwave >= LTILES) return;
    int lane = t & 63;
    int m = lane & 15, kg = lane >> 4;
    int r0 = gwave * 16;

    // B fragments: B[k][n], n = lane&15, k = kb*32 + kg*8 + j  (W 32 KB, hot)
    half8 fb[4][4];
#pragma unroll
    for (int kb = 0; kb < 4; ++kb)
#pragma unroll
        for (int nb = 0; nb < 4; ++nb) {
            const float* wp = W + (size_t)(kb * 32 + kg * 8) * OUT_F + nb * 16 + m;
#pragma unroll
            for (int j = 0; j < 8; ++j)
                fb[kb][nb][j] = (_Float16)wp[j * OUT_F];
        }

    f32x4 acc[4];
#pragma unroll
    for (int nb = 0; nb < 4; ++nb) acc[nb] = (f32x4){0.f, 0.f, 0.f, 0.f};

#pragma unroll
    for (int kb = 0; kb < 4; ++kb) {
        const float4* ap = (const float4*)(feat + (size_t)(r0 + m) * IN_F + kb * 32 + kg * 8);
        float4 a0 = ap[0], a1 = ap[1];
        half8 fa = {(_Float16)a0.x, (_Float16)a0.y, (_Float16)a0.z, (_Float16)a0.w,
                    (_Float16)a1.x, (_Float16)a1.y, (_Float16)a1.z, (_Float16)a1.w};
#pragma unroll
        for (int nb = 0; nb < 4; ++nb)
            acc[nb] = __builtin_amdgcn_mfma_f32_16x16x32_f16(fa, fb[kb][nb], acc[nb], 0, 0, 0);
    }
    // D: col = lane&15, row = (lane>>4)*4 + i
#pragma unroll
    for (int nb = 0; nb < 4; ++nb)
#pragma unroll
        for (int i = 0; i < 4; ++i)
            fth[(size_t)(r0 + kg * 4 + i) * OUT_F + nb * 16 + m] = __float2half_rn(acc[nb][i]);
}

// one block per bucket: per-node counts + scan -> row_beg/row_end, then place
// src ids into exact CSR slots (capacity layout). One block -> full lines.
__global__ __launch_bounds__(256) void place_kernel(const unsigned* __restrict__ staging,
                                                    const int* __restrict__ bcursor,
                                                    int* __restrict__ row_beg,
                                                    int* __restrict__ row_end,
                                                    int* __restrict__ edge_src) {
    __shared__ int cnt[BKT_NODES], sc[256], lcur[BKT_NODES];
    int t = threadIdx.x;
    cnt[t] = 0; cnt[t + 256] = 0;
    __syncthreads();
    int base = blockIdx.x * BKT_CAP;
    int n = bcursor[blockIdx.x];
    for (int i = t; i < n; i += 256)
        atomicAdd(&cnt[staging[base + i] >> 17], 1);
    __syncthreads();
    int v0 = cnt[2 * t], v1 = cnt[2 * t + 1];
    int ts = v0 + v1;
    sc[t] = ts;
    __syncthreads();
    for (int off = 1; off < 256; off <<= 1) {
        int add = (t >= off) ? sc[t - off] : 0;
        __syncthreads();
        sc[t] += add;
        __syncthreads();
    }
    int excl = sc[t] - ts;
    int node0 = blockIdx.x * BKT_NODES;
    int b0 = base + excl, b1 = base + excl + v0;
    lcur[2 * t]     = b0;
    lcur[2 * t + 1] = b1;
    if (node0 + 2 * t < N_NODES)     { row_beg[node0 + 2 * t] = b0;     row_end[node0 + 2 * t] = b0 + v0; }
    if (node0 + 2 * t + 1 < N_NODES) { row_beg[node0 + 2 * t + 1] = b1; row_end[node0 + 2 * t + 1] = b1 + v1; }
    __syncthreads();
    for (int i = base + t; i < base + n; i += 256) {
        unsigned u = staging[i];
        int pos = atomicAdd(&lcur[u >> 17], 1);
        edge_src[pos] = (int)(u & 0x1FFFFu);
    }
}

// one wave per dst node; 16 lanes/edge, 8 edges in flight. exp2-domain
// online softmax, packed-f32 (v_pk_fma) channel-pair accumulators.
// Invalid edges score -1e30; a never-valid quarter's garbage state is
// annihilated at merge by exp2(-1e30 - M) == 0.
__global__ __launch_bounds__(256) void fused_node_kernel(const __half* __restrict__ fth,
                                                         const int* __restrict__ row_beg,
                                                         const int* __restrict__ row_end,
                                                         const int* __restrict__ edge_src,
                                                         float* __restrict__ out) {
    const float LOG2E = 1.44269504088896340736f;
    int wave = (blockIdx.x * 256 + threadIdx.x) >> 6;
    int lane = threadIdx.x & 63;
    if (wave >= N_NODES) return;
    int q = lane >> 4, ql = lane & 15;

    int beg = row_beg[wave];
    int end = row_end[wave];

    float2 rd = *(const float2*)(fth + (size_t)wave * OUT_F + 4 * ql);
    f2v fd01 = __builtin_convertvector(*(h2v*)&rd.x, f2v);
    f2v fd23 = __builtin_convertvector(*(h2v*)&rd.y, f2v);

    float m = -1e30f, l = 0.f;
    f2v a01 = (f2v){0.f, 0.f}, a23 = (f2v){0.f, 0.f};

    for (int i = beg; i < end; i += 8) {
        int eA = i + q, eB = i + 4 + q;
        bool vAv = eA < end, vBv = eB < end;
        int sA = edge_src[vAv ? eA : beg];
        int sB = edge_src[vBv ? eB : beg];
        float2 rA = *(const float2*)(fth + (size_t)sA * OUT_F + 4 * ql);
        float2 rB = *(const float2*)(fth + (size_t)sB * OUT_F + 4 * ql);
        f2v vA01 = __builtin_convertvector(*(h2v*)&rA.x, f2v);
        f2v vA23 = __builtin_convertvector(*(h2v*)&rA.y, f2v);
        f2v vB01 = __builtin_convertvector(*(h2v*)&rB.x, f2v);
        f2v vB23 = __builtin_convertvector(*(h2v*)&rB.y, f2v);

        f2v tA = vA01 * fd01 + vA23 * fd23;
        f2v tB = vB01 * fd01 + vB23 * fd23;
        float pA = tA.x + tA.y;
        float pB = tB.x + tB.y;
#pragma unroll
        for (int dd = 1; dd < 16; dd <<= 1) {
            pA += __shfl_xor(pA, dd);
            pB += __shfl_xor(pB, dd);
        }
        pA = vAv ? pA * LOG2E : -1e30f;
        pB = vBv ? pB * LOG2E : -1e30f;
        float nm = fmaxf(fmaxf(m, pA), pB);
        float alpha = exp2f(m - nm);
        float wA = exp2f(pA - nm);
        float wB = exp2f(pB - nm);
        l = l * alpha + (wA + wB);
        a01 = a01 * alpha + vA01 * wA + vB01 * wB;
        a23 = a23 * alpha + vA23 * wA + vB23 * wB;
        m = nm;
    }

    // merge the 4 quarter-states (xor16, then xor32) in exp2 domain
#pragma unroll
    for (int dd = 16; dd <= 32; dd <<= 1) {
        float m2 = __shfl_xor(m, dd), l2 = __shfl_xor(l, dd);
        f2v b01, b23;
        b01.x = __shfl_xor(a01.x, dd); b01.y = __shfl_xor(a01.y, dd);
        b23.x = __shfl_xor(a23.x, dd); b23.y = __shfl_xor(a23.y, dd);
        float M = fmaxf(m, m2);
        float e1 = exp2f(m - M), e2 = exp2f(m2 - M);
        l = l * e1 + l2 * e2;
        a01 = a01 * e1 + b01 * e2;
        a23 = a23 * e1 + b23 * e2;
        m = M;
    }
    if (q == 0) {
        float inv = (l > 0.f) ? 1.f / l : 0.f;
        *(float4*)(out + (size_t)wave * OUT_F + 4 * ql) =
            make_float4(a01.x * inv, a01.y * inv, a23.x * inv, a23.y * inv);
    }
}

extern "C" void kernel_launch(void* const* d_in, const int* in_sizes, int n_in,
                              void* d_out, int out_size, void* d_ws, size_t ws_size,
                              hipStream_t stream) {
    const float* feat = (const float*)d_in[0];
    const float* W    = (const float*)d_in[1];
    const int*   src  = (const int*)d_in[2];
    const int*   dst  = (const int*)d_in[3];
    float* out = (float*)d_out;

    __half*   fth      = (__half*)d_ws;
    unsigned* staging  = (unsigned*)((int*)d_ws + (size_t)N_NODES * OUT_F / 2);
    int*      edge_src = (int*)(staging + (size_t)K_BKT * BKT_CAP);
    int*      bcursor  = edge_src + (size_t)K_BKT * BKT_CAP;
    int*      row_beg  = bcursor + K_BKT;
    int*      row_end  = row_beg + N_NODES;

    hipMemsetAsync(bcursor, 0, K_BKT * sizeof(int), stream);
    partition_linear_kernel<<<PBLKS + LBLKS, 256, 0, stream>>>(src, dst, bcursor, staging,
                                                               feat, W, fth);
    place_kernel<<<K_BKT, 256, 0, stream>>>(staging, bcursor, row_beg, row_end, edge_src);
    fused_node_kernel<<<(N_NODES * 64) / 256, 256, 0, stream>>>(fth, row_beg, row_end, edge_src, out);
}

// Round 10
// 201.352 us; speedup vs baseline: 1.3062x; 1.0010x over previous
//
#include <hip/hip_runtime.h>
#include <hip/hip_fp16.h>
#include <math.h>

#define N_NODES 100000
#define N_EDGES 1600000
#define IN_F    128
#define OUT_F   64
#define K_BKT     196                            // dst buckets of 512 nodes
#define BKT_SHIFT 9
#define BKT_NODES 512
#define BKT_CAP   10240                          // slots per bucket (E=8192, +22 sigma)
#define CHUNK     4096                           // partition block edge count
#define PBLKS     ((N_EDGES + CHUNK - 1) / CHUNK)          // 391
#define LTILES    (N_NODES / 16)                 // 6250 exact 16-row MFMA tiles
#define LBLKS     ((LTILES + 3) / 4)             // 1563 (4 waves/block)

typedef _Float16 half8 __attribute__((ext_vector_type(8)));
typedef float    f32x4 __attribute__((ext_vector_type(4)));

// ---------------- workspace layout (4-byte units) ----------------
// fth      : N_NODES*OUT_F/2       (fp16 projected features, 12.8 MB)
// staging  : K_BKT*BKT_CAP uint    (packed src|dloc<<17, capacity layout, 8 MB)
// edge_src : K_BKT*BKT_CAP int     (CSR src ids, capacity layout, 8 MB)
// bcursor  : K_BKT                 (zero-init; after partition = bucket count)
// row_beg/row_end : N_NODES each

// blocks [0,PBLKS): in-LDS counting sort of a 4096-edge chunk into bucket
// regions at b*BKT_CAP (reservation atomics on 196 spread counters).
// blocks [PBLKS,..): MFMA fp16 linear — wave = 16-row tile of ft = feat @ W.
__global__ __launch_bounds__(256) void partition_linear_kernel(const int* __restrict__ src,
                                                               const int* __restrict__ dst,
                                                               int* __restrict__ bcursor,
                                                               unsigned* __restrict__ staging,
                                                               const float* __restrict__ feat,
                                                               const float* __restrict__ W,
                                                               __half* __restrict__ fth) {
    __shared__ int hist[256], lbase[256], gbase[256], sc[256];
    __shared__ unsigned sval[CHUNK];
    __shared__ int spos[CHUNK];
    int t = threadIdx.x;
    if (blockIdx.x < PBLKS) {
        hist[t] = 0;
        __syncthreads();
        int beg = blockIdx.x * CHUNK;
        int end = min(beg + CHUNK, N_EDGES);
        for (int i = beg + t; i < end; i += 256)
            atomicAdd(&hist[dst[i] >> BKT_SHIFT], 1);
        __syncthreads();
        int v = hist[t];
        sc[t] = v;
        __syncthreads();
        for (int off = 1; off < 256; off <<= 1) {
            int add = (t >= off) ? sc[t - off] : 0;
            __syncthreads();
            sc[t] += add;
            __syncthreads();
        }
        lbase[t] = sc[t] - v;                    // block-local exclusive
        if (t < K_BKT && v) gbase[t] = t * BKT_CAP + atomicAdd(&bcursor[t], v);
        hist[t] = 0;                             // reuse as rank counter
        __syncthreads();
        for (int i = beg + t; i < end; i += 256) {
            int s = src[i], d = dst[i];
            int b = d >> BKT_SHIFT;
            int r = atomicAdd(&hist[b], 1);
            int lp = lbase[b] + r;
            sval[lp] = (unsigned)s | ((unsigned)(d & (BKT_NODES - 1)) << 17);
            spos[lp] = gbase[b] + r;
        }
        __syncthreads();
        int n = end - beg;
        for (int p = t; p < n; p += 256) staging[spos[p]] = sval[p];
        return;
    }
    // ---- MFMA linear: one wave per 16-row tile ----
    int gwave = (blockIdx.x - PBLKS) * 4 + (t >> 6);
    if (gwave >= LTILES) return;
    int lane = t & 63;
    int m = lane & 15, kg = lane >> 4;
    int r0 = gwave * 16;

    // B fragments: B[k][n], n = lane&15, k = kb*32 + kg*8 + j  (W 32 KB, hot)
    half8 fb[4][4];
#pragma unroll
    for (int kb = 0; kb < 4; ++kb)
#pragma unroll
        for (int nb = 0; nb < 4; ++nb) {
            const float* wp = W + (size_t)(kb * 32 + kg * 8) * OUT_F + nb * 16 + m;
#pragma unroll
            for (int j = 0; j < 8; ++j)
                fb[kb][nb][j] = (_Float16)wp[j * OUT_F];
        }

    f32x4 acc[4];
#pragma unroll
    for (int nb = 0; nb < 4; ++nb) acc[nb] = (f32x4){0.f, 0.f, 0.f, 0.f};

#pragma unroll
    for (int kb = 0; kb < 4; ++kb) {
        const float4* ap = (const float4*)(feat + (size_t)(r0 + m) * IN_F + kb * 32 + kg * 8);
        float4 a0 = ap[0], a1 = ap[1];
        half8 fa = {(_Float16)a0.x, (_Float16)a0.y, (_Float16)a0.z, (_Float16)a0.w,
                    (_Float16)a1.x, (_Float16)a1.y, (_Float16)a1.z, (_Float16)a1.w};
#pragma unroll
        for (int nb = 0; nb < 4; ++nb)
            acc[nb] = __builtin_amdgcn_mfma_f32_16x16x32_f16(fa, fb[kb][nb], acc[nb], 0, 0, 0);
    }
    // D: col = lane&15, row = (lane>>4)*4 + i
#pragma unroll
    for (int nb = 0; nb < 4; ++nb)
#pragma unroll
        for (int i = 0; i < 4; ++i)
            fth[(size_t)(r0 + kg * 4 + i) * OUT_F + nb * 16 + m] = __float2half_rn(acc[nb][i]);
}

// one block per bucket: per-node counts + scan -> row_beg/row_end, then place
// src ids into exact CSR slots (capacity layout). One block -> full lines.
__global__ __launch_bounds__(256) void place_kernel(const unsigned* __restrict__ staging,
                                                    const int* __restrict__ bcursor,
                                                    int* __restrict__ row_beg,
                                                    int* __restrict__ row_end,
                                                    int* __restrict__ edge_src) {
    __shared__ int cnt[BKT_NODES], sc[256], lcur[BKT_NODES];
    int t = threadIdx.x;
    cnt[t] = 0; cnt[t + 256] = 0;
    __syncthreads();
    int base = blockIdx.x * BKT_CAP;
    int n = bcursor[blockIdx.x];
    for (int i = t; i < n; i += 256)
        atomicAdd(&cnt[staging[base + i] >> 17], 1);
    __syncthreads();
    int v0 = cnt[2 * t], v1 = cnt[2 * t + 1];
    int ts = v0 + v1;
    sc[t] = ts;
    __syncthreads();
    for (int off = 1; off < 256; off <<= 1) {
        int add = (t >= off) ? sc[t - off] : 0;
        __syncthreads();
        sc[t] += add;
        __syncthreads();
    }
    int excl = sc[t] - ts;
    int node0 = blockIdx.x * BKT_NODES;
    int b0 = base + excl, b1 = base + excl + v0;
    lcur[2 * t]     = b0;
    lcur[2 * t + 1] = b1;
    if (node0 + 2 * t < N_NODES)     { row_beg[node0 + 2 * t] = b0;     row_end[node0 + 2 * t] = b0 + v0; }
    if (node0 + 2 * t + 1 < N_NODES) { row_beg[node0 + 2 * t + 1] = b1; row_end[node0 + 2 * t + 1] = b1 + v1; }
    __syncthreads();
    for (int i = base + t; i < base + n; i += 256) {
        unsigned u = staging[i];
        int pos = atomicAdd(&lcur[u >> 17], 1);
        edge_src[pos] = (int)(u & 0x1FFFFu);
    }
}

// one wave per dst node; 16 lanes/edge (4 fp16 channels/lane), 16 edges in
// flight (4 chains per quarter). Scores computed directly in log2 domain by
// pre-scaling the dst fragment with log2(e); one softmax rescale per 16
// edges. Invalid slots score -1e30 -> weight exp2()==0.
__global__ __launch_bounds__(256) void fused_node_kernel(const __half* __restrict__ fth,
                                                         const int* __restrict__ row_beg,
                                                         const int* __restrict__ row_end,
                                                         const int* __restrict__ edge_src,
                                                         float* __restrict__ out) {
    const float LOG2E = 1.44269504088896340736f;
    int wave = (blockIdx.x * 256 + threadIdx.x) >> 6;
    int lane = threadIdx.x & 63;
    if (wave >= N_NODES) return;
    int q = lane >> 4, ql = lane & 15;

    int beg = row_beg[wave];
    int end = row_end[wave];

    float2 rd = *(const float2*)(fth + (size_t)wave * OUT_F + 4 * ql);
    __half2 d01 = *(__half2*)&rd.x, d23 = *(__half2*)&rd.y;
    float fd0 = __half2float(d01.x) * LOG2E, fd1 = __half2float(d01.y) * LOG2E;
    float fd2 = __half2float(d23.x) * LOG2E, fd3 = __half2float(d23.y) * LOG2E;

    float m = -1e30f, l = 0.f;
    float a0 = 0.f, a1 = 0.f, a2 = 0.f, a3 = 0.f;

    for (int i = beg; i < end; i += 16) {
        int e0 = i + q, e1 = e0 + 4, e2 = e0 + 8, e3 = e0 + 12;
        bool u0 = e0 < end, u1 = e1 < end, u2 = e2 < end, u3 = e3 < end;
        int s0 = edge_src[u0 ? e0 : beg];
        int s1 = edge_src[u1 ? e1 : beg];
        int s2 = edge_src[u2 ? e2 : beg];
        int s3 = edge_src[u3 ? e3 : beg];
        float2 r0 = *(const float2*)(fth + (size_t)s0 * OUT_F + 4 * ql);
        float2 r1 = *(const float2*)(fth + (size_t)s1 * OUT_F + 4 * ql);
        float2 r2 = *(const float2*)(fth + (size_t)s2 * OUT_F + 4 * ql);
        float2 r3 = *(const float2*)(fth + (size_t)s3 * OUT_F + 4 * ql);
        __half2 A01 = *(__half2*)&r0.x, A23 = *(__half2*)&r0.y;
        __half2 B01 = *(__half2*)&r1.x, B23 = *(__half2*)&r1.y;
        __half2 C01 = *(__half2*)&r2.x, C23 = *(__half2*)&r2.y;
        __half2 D01 = *(__half2*)&r3.x, D23 = *(__half2*)&r3.y;
        float vA0 = __half2float(A01.x), vA1 = __half2float(A01.y);
        float vA2 = __half2float(A23.x), vA3 = __half2float(A23.y);
        float vB0 = __half2float(B01.x), vB1 = __half2float(B01.y);
        float vB2 = __half2float(B23.x), vB3 = __half2float(B23.y);
        float vC0 = __half2float(C01.x), vC1 = __half2float(C01.y);
        float vC2 = __half2float(C23.x), vC3 = __half2float(C23.y);
        float vD0 = __half2float(D01.x), vD1 = __half2float(D01.y);
        float vD2 = __half2float(D23.x), vD3 = __half2float(D23.y);

        float p0 = vA0 * fd0 + vA1 * fd1 + vA2 * fd2 + vA3 * fd3;
        float p1 = vB0 * fd0 + vB1 * fd1 + vB2 * fd2 + vB3 * fd3;
        float p2 = vC0 * fd0 + vC1 * fd1 + vC2 * fd2 + vC3 * fd3;
        float p3 = vD0 * fd0 + vD1 * fd1 + vD2 * fd2 + vD3 * fd3;
#pragma unroll
        for (int dd = 1; dd < 16; dd <<= 1) {
            p0 += __shfl_xor(p0, dd);
            p1 += __shfl_xor(p1, dd);
            p2 += __shfl_xor(p2, dd);
            p3 += __shfl_xor(p3, dd);
        }
        if (!u0) p0 = -1e30f;
        if (!u1) p1 = -1e30f;
        if (!u2) p2 = -1e30f;
        if (!u3) p3 = -1e30f;
        float nm = fmaxf(fmaxf(fmaxf(p0, p1), fmaxf(p2, p3)), m);
        float alpha = exp2f(m - nm);
        float w0 = exp2f(p0 - nm), w1 = exp2f(p1 - nm);
        float w2 = exp2f(p2 - nm), w3 = exp2f(p3 - nm);
        l = l * alpha + ((w0 + w1) + (w2 + w3));
        a0 = a0 * alpha + (w0 * vA0 + w1 * vB0) + (w2 * vC0 + w3 * vD0);
        a1 = a1 * alpha + (w0 * vA1 + w1 * vB1) + (w2 * vC1 + w3 * vD1);
        a2 = a2 * alpha + (w0 * vA2 + w1 * vB2) + (w2 * vC2 + w3 * vD2);
        a3 = a3 * alpha + (w0 * vA3 + w1 * vB3) + (w2 * vC3 + w3 * vD3);
        m = nm;
    }

    // merge the 4 quarter-states (xor16, then xor32) in log2 domain
#pragma unroll
    for (int dd = 16; dd <= 32; dd <<= 1) {
        float m2 = __shfl_xor(m, dd), l2 = __shfl_xor(l, dd);
        float b0 = __shfl_xor(a0, dd), b1 = __shfl_xor(a1, dd);
        float b2 = __shfl_xor(a2, dd), b3 = __shfl_xor(a3, dd);
        float M = fmaxf(m, m2);
        float e1 = exp2f(m - M), e2 = exp2f(m2 - M);
        l = l * e1 + l2 * e2;
        a0 = a0 * e1 + b0 * e2;
        a1 = a1 * e1 + b1 * e2;
        a2 = a2 * e1 + b2 * e2;
        a3 = a3 * e1 + b3 * e2;
        m = M;
    }
    if (q == 0) {
        float inv = (l > 0.f) ? 1.f / l : 0.f;
        *(float4*)(out + (size_t)wave * OUT_F + 4 * ql) =
            make_float4(a0 * inv, a1 * inv, a2 * inv, a3 * inv);
    }
}

extern "C" void kernel_launch(void* const* d_in, const int* in_sizes, int n_in,
                              void* d_out, int out_size, void* d_ws, size_t ws_size,
                              hipStream_t stream) {
    const float* feat = (const float*)d_in[0];
    const float* W    = (const float*)d_in[1];
    const int*   src  = (const int*)d_in[2];
    const int*   dst  = (const int*)d_in[3];
    float* out = (float*)d_out;

    __half*   fth      = (__half*)d_ws;
    unsigned* staging  = (unsigned*)((int*)d_ws + (size_t)N_NODES * OUT_F / 2);
    int*      edge_src = (int*)(staging + (size_t)K_BKT * BKT_CAP);
    int*      bcursor  = edge_src + (size_t)K_BKT * BKT_CAP;
    int*      row_beg  = bcursor + K_BKT;
    int*      row_end  = row_beg + N_NODES;

    hipMemsetAsync(bcursor, 0, K_BKT * sizeof(int), stream);
    partition_linear_kernel<<<PBLKS + LBLKS, 256, 0, stream>>>(src, dst, bcursor, staging,
                                                               feat, W, fth);
    place_kernel<<<K_BKT, 256, 0, stream>>>(staging, bcursor, row_beg, row_end, edge_src);
    fused_node_kernel<<<(N_NODES * 64) / 256, 256, 0, stream>>>(fth, row_beg, row_end, edge_src, out);
}